// Round 1
// baseline (311.401 us; speedup 1.0000x reference)
//
#include <hip/hip_runtime.h>
#include <hip/hip_bf16.h>
#include <cstdint>

// ---------------------------------------------------------------------------
// AttentionModel: out = softmax((xWq^T+bq)(xWk^T+bk)^T / sqrt(E)) (xWv^T+bv)
// B=4, S=2048, E=1024, fp32 in/out.  Strategy: bf16 MFMA everywhere
// (error budget analysis: output error ~1e-3 << 6.5e-3 threshold because
// attention weights are diffuse, sqrt(sum p^2) ~ 0.036).
// GEMM core: m97 recipe — 128x128 tile, BK=32, global_load_lds width 16,
// mfma_f32_16x16x32_bf16, 4 waves x (4x4) 16x16 frags.
// ---------------------------------------------------------------------------

typedef __attribute__((ext_vector_type(8))) short bf16x8;
typedef __attribute__((ext_vector_type(4))) float f32x4;

__device__ __forceinline__ unsigned short f2bf(float f) {
  union { float f; uint32_t u; } x; x.f = f;
  uint32_t u = x.u;
  return (unsigned short)((u + 0x7fffu + ((u >> 16) & 1u)) >> 16);  // RNE
}
__device__ __forceinline__ float bf2f(unsigned short h) {
  union { uint32_t u; float f; } x; x.u = ((uint32_t)h) << 16;
  return x.f;
}

__device__ __forceinline__ void async_copy16(const void* g, void* l) {
  __builtin_amdgcn_global_load_lds(
      (const __attribute__((address_space(1))) void*)g,
      (__attribute__((address_space(3))) void*)l, 16, 0, 0);
}

// ---------------------------------------------------------------------------
// fp32 -> bf16 convert, 4 elems/thread, exact-size grid
// ---------------------------------------------------------------------------
__global__ __launch_bounds__(256) void convert_f32_to_bf16(
    const float* __restrict__ in, unsigned short* __restrict__ out, int n4) {
  int i = blockIdx.x * blockDim.x + threadIdx.x;
  if (i >= n4) return;
  const float4 v = ((const float4*)in)[i];
  ushort4 o;
  o.x = f2bf(v.x); o.y = f2bf(v.y); o.z = f2bf(v.z); o.w = f2bf(v.w);
  ((ushort4*)out)[i] = o;
}

// ---------------------------------------------------------------------------
// C[M,N] = scale * (A[M,K] x B[N,K]^T) (+ bias[col]); bf16 A/B, fp32 acc.
// 256 threads = 4 waves; wave w owns 64x64 quadrant (4x4 MFMA frags).
// LDS layout forced flat [128][32] by global_load_lds (wave-uniform base +
// lane*16); no padding possible (G: guide §5 caveat).
// ---------------------------------------------------------------------------
template <bool HAS_BIAS, bool OUT_BF16>
__global__ __launch_bounds__(256) void gemm_bt(
    const unsigned short* __restrict__ Ab, const unsigned short* __restrict__ Bb,
    unsigned short* __restrict__ Cb, float* __restrict__ Cf,
    const float* __restrict__ bias0, const float* __restrict__ bias1,
    const float* __restrict__ bias2,
    int K, int N, float scale, long sA, long sB, long sC) {
  __shared__ unsigned short As[128 * 32];
  __shared__ unsigned short Bs[128 * 32];

  const int z = blockIdx.z;
  const unsigned short* A = Ab + (long)z * sA;
  const unsigned short* Bm = Bb + (long)z * sB;

  const int tid  = threadIdx.x;
  const int lane = tid & 63;
  const int wave = tid >> 6;
  const int l15  = lane & 15;
  const int quad = lane >> 4;
  const int wm = (wave >> 1) * 64;
  const int wn = (wave & 1) * 64;

  const int tile_m = blockIdx.x * 128;
  const int tile_n = blockIdx.y * 128;

  // staging: each wave covers 16 rows (64 lanes * 8 bf16 = 16 rows of 32)
  const int srow = wave * 16 + (lane >> 2);
  const int scol = (lane & 3) * 8;

  f32x4 acc[4][4] = {};

  for (int k0 = 0; k0 < K; k0 += 32) {
    __syncthreads();  // previous-iter LDS readers done
#pragma unroll
    for (int p = 0; p < 2; ++p) {
      const unsigned short* ga = A + (long)(tile_m + p * 64 + srow) * K + (k0 + scol);
      async_copy16(ga, &As[(p * 64 + wave * 16) * 32]);
      const unsigned short* gb = Bm + (long)(tile_n + p * 64 + srow) * K + (k0 + scol);
      async_copy16(gb, &Bs[(p * 64 + wave * 16) * 32]);
    }
    __syncthreads();  // vmcnt(0) drain: LDS tile ready

    bf16x8 af[4], bfr[4];
#pragma unroll
    for (int i = 0; i < 4; ++i)
      af[i] = *(const bf16x8*)&As[(wm + i * 16 + l15) * 32 + quad * 8];
#pragma unroll
    for (int j = 0; j < 4; ++j)
      bfr[j] = *(const bf16x8*)&Bs[(wn + j * 16 + l15) * 32 + quad * 8];
#pragma unroll
    for (int i = 0; i < 4; ++i)
#pragma unroll
      for (int j = 0; j < 4; ++j)
        acc[i][j] = __builtin_amdgcn_mfma_f32_16x16x32_bf16(af[i], bfr[j], acc[i][j], 0, 0, 0);
  }

  // epilogue: C/D layout col=lane&15, row=quad*4+reg (guide §3, m89-verified)
  const float* bias = bias0;
  if (HAS_BIAS) { if (z == 1) bias = bias1; else if (z == 2) bias = bias2; }

  unsigned short* Cbz = Cb ? Cb + (long)z * sC : nullptr;
  float* Cfz = Cf ? Cf + (long)z * sC : nullptr;

#pragma unroll
  for (int j = 0; j < 4; ++j) {
    const int col = tile_n + wn + j * 16 + l15;
    const float bv = HAS_BIAS ? bias[col] : 0.0f;
#pragma unroll
    for (int i = 0; i < 4; ++i) {
      const int row0 = tile_m + wm + i * 16 + quad * 4;
#pragma unroll
      for (int r = 0; r < 4; ++r) {
        const float v = acc[i][j][r] * scale + bv;
        if (OUT_BF16) Cbz[(long)(row0 + r) * N + col] = f2bf(v);
        else          Cfz[(long)(row0 + r) * N + col] = v;
      }
    }
  }
}

// ---------------------------------------------------------------------------
// V [b][s][f] -> VT [b][f][s]   (bf16, 32x32 LDS tiles, padded)
// ---------------------------------------------------------------------------
__global__ void transpose_v(const unsigned short* __restrict__ V,
                            unsigned short* __restrict__ VT) {
  __shared__ unsigned short t[32][33];
  const int b  = blockIdx.z;
  const int s0 = blockIdx.x * 32;
  const int f0 = blockIdx.y * 32;
  const int tx = threadIdx.x;  // 0..31
  const int ty = threadIdx.y;  // 0..7
  const unsigned short* Vb = V + (long)b * 2048 * 1024;
  unsigned short* VTb = VT + (long)b * 1024 * 2048;
#pragma unroll
  for (int j = 0; j < 4; ++j)
    t[ty + j * 8][tx] = Vb[(long)(s0 + ty + j * 8) * 1024 + f0 + tx];
  __syncthreads();
#pragma unroll
  for (int j = 0; j < 4; ++j)
    VTb[(long)(f0 + ty + j * 8) * 2048 + s0 + tx] = t[tx][ty + j * 8];
}

// ---------------------------------------------------------------------------
// In-place row softmax over bf16 scores: 8192 rows x 2048. One block/row,
// 256 threads x 8 elems, fp32 math.
// ---------------------------------------------------------------------------
__global__ __launch_bounds__(256) void softmax_rows(unsigned short* __restrict__ S) {
  __shared__ float red[4];
  unsigned short* p = S + (long)blockIdx.x * 2048;
  const int tid = threadIdx.x;

  uint4 raw = ((const uint4*)p)[tid];  // 8 bf16
  const uint32_t* rw = (const uint32_t*)&raw;
  float v[8];
#pragma unroll
  for (int i = 0; i < 4; ++i) {
    v[2 * i]     = bf2f((unsigned short)(rw[i] & 0xffffu));
    v[2 * i + 1] = bf2f((unsigned short)(rw[i] >> 16));
  }
  float m = v[0];
#pragma unroll
  for (int i = 1; i < 8; ++i) m = fmaxf(m, v[i]);
#pragma unroll
  for (int o = 32; o > 0; o >>= 1) m = fmaxf(m, __shfl_xor(m, o));
  const int wv = tid >> 6;
  if ((tid & 63) == 0) red[wv] = m;
  __syncthreads();
  m = fmaxf(fmaxf(red[0], red[1]), fmaxf(red[2], red[3]));

  float s = 0.0f;
#pragma unroll
  for (int i = 0; i < 8; ++i) { v[i] = __expf(v[i] - m); s += v[i]; }
#pragma unroll
  for (int o = 32; o > 0; o >>= 1) s += __shfl_xor(s, o);
  __syncthreads();  // protect red before reuse
  if ((tid & 63) == 0) red[wv] = s;
  __syncthreads();
  s = red[0] + red[1] + red[2] + red[3];
  const float inv = 1.0f / s;

  uint32_t outw[4];
#pragma unroll
  for (int i = 0; i < 4; ++i) {
    const unsigned short lo = f2bf(v[2 * i] * inv);
    const unsigned short hi = f2bf(v[2 * i + 1] * inv);
    outw[i] = (uint32_t)lo | ((uint32_t)hi << 16);
  }
  ((uint4*)p)[tid] = *(uint4*)outw;
}

// ---------------------------------------------------------------------------
extern "C" void kernel_launch(void* const* d_in, const int* in_sizes, int n_in,
                              void* d_out, int out_size, void* d_ws, size_t ws_size,
                              hipStream_t stream) {
  const float* x  = (const float*)d_in[0];
  const float* Wq = (const float*)d_in[1];
  const float* bq = (const float*)d_in[2];
  const float* Wk = (const float*)d_in[3];
  const float* bk = (const float*)d_in[4];
  const float* Wv = (const float*)d_in[5];
  const float* bv = (const float*)d_in[6];
  float* out = (float*)d_out;

  constexpr int Bt = 4, S = 2048, E = 1024;
  constexpr int M = Bt * S;  // 8192 tokens

  // ws layout (bf16 unless noted): x_bf | W_bf(3) | Q | K | V | VT | P(scores)
  unsigned short* xb  = (unsigned short*)d_ws;
  unsigned short* Wb  = xb + (size_t)M * E;          // 3 * E*E
  unsigned short* QKV = Wb + (size_t)3 * E * E;      // 3 * M*E
  unsigned short* Q   = QKV;
  unsigned short* Kb  = QKV + (size_t)M * E;
  unsigned short* V   = QKV + (size_t)2 * M * E;
  unsigned short* VT  = QKV + (size_t)3 * M * E;     // M*E
  unsigned short* P   = VT + (size_t)M * E;          // Bt*S*S
  // total = (M*E*5 + 3*E*E + Bt*S*S) * 2 B ~= 124 MB

  // 1) converts
  convert_f32_to_bf16<<<dim3(M * E / 4 / 256), dim3(256), 0, stream>>>(x, xb, M * E / 4);
  convert_f32_to_bf16<<<dim3(E * E / 4 / 256), dim3(256), 0, stream>>>(Wq, Wb, E * E / 4);
  convert_f32_to_bf16<<<dim3(E * E / 4 / 256), dim3(256), 0, stream>>>(Wk, Wb + (size_t)E * E, E * E / 4);
  convert_f32_to_bf16<<<dim3(E * E / 4 / 256), dim3(256), 0, stream>>>(Wv, Wb + (size_t)2 * E * E, E * E / 4);

  // 2) projections: z in {Q,K,V}; y = x * W^T + b
  gemm_bt<true, true><<<dim3(M / 128, E / 128, 3), dim3(256), 0, stream>>>(
      xb, Wb, QKV, nullptr, bq, bk, bv, E, E, 1.0f,
      0L, (long)E * E, (long)M * E);

  // 3) V -> VT
  transpose_v<<<dim3(S / 32, E / 32, Bt), dim3(32, 8), 0, stream>>>(V, VT);

  // 4) scores = Q K^T / 32   (per-batch via z)
  gemm_bt<false, true><<<dim3(S / 128, S / 128, Bt), dim3(256), 0, stream>>>(
      Q, Kb, P, nullptr, nullptr, nullptr, nullptr, E, S, 1.0f / 32.0f,
      (long)S * E, (long)S * E, (long)S * S);

  // 5) softmax rows (in place)
  softmax_rows<<<dim3(M), dim3(256), 0, stream>>>(P);

  // 6) out = P V = P * (VT)^T   (fp32 out)
  gemm_bt<false, false><<<dim3(S / 128, E / 128, Bt), dim3(256), 0, stream>>>(
      P, VT, nullptr, out, nullptr, nullptr, nullptr, S, E, 1.0f,
      (long)S * S, (long)E * S, (long)S * E);
}

// Round 2
// 295.110 us; speedup vs baseline: 1.0552x; 1.0552x over previous
//
#include <hip/hip_runtime.h>
#include <hip/hip_bf16.h>
#include <cstdint>

// ---------------------------------------------------------------------------
// AttentionModel: out = softmax((xWq^T+bq)(xWk^T+bk)^T / sqrt(E)) (xWv^T+bv)
// B=4, S=2048, E=1024, fp32 in/out.  bf16 MFMA pipeline.
// R1 change: LDS granule swizzle kills the 4-way bank conflict on
// ds_read_b128 fragment reads (slot = row*4 + ((kc + (row>>1)) & 3)).
// Staging picks the matching global column per lane (free — global_load_lds
// dst is forced to base+lane*16, but src is per-lane).
// ---------------------------------------------------------------------------

typedef __attribute__((ext_vector_type(8))) short bf16x8;
typedef __attribute__((ext_vector_type(4))) float f32x4;

__device__ __forceinline__ unsigned short f2bf(float f) {
  union { float f; uint32_t u; } x; x.f = f;
  uint32_t u = x.u;
  return (unsigned short)((u + 0x7fffu + ((u >> 16) & 1u)) >> 16);  // RNE
}
__device__ __forceinline__ float bf2f(unsigned short h) {
  union { uint32_t u; float f; } x; x.u = ((uint32_t)h) << 16;
  return x.f;
}

__device__ __forceinline__ void async_copy16(const void* g, void* l) {
  __builtin_amdgcn_global_load_lds(
      (const __attribute__((address_space(1))) void*)g,
      (__attribute__((address_space(3))) void*)l, 16, 0, 0);
}

// ---------------------------------------------------------------------------
// One merged fp32->bf16 convert for x, Wq, Wk, Wv (saves 3 launches)
// ---------------------------------------------------------------------------
__global__ __launch_bounds__(256) void convert_all(
    const float* __restrict__ x, const float* __restrict__ Wq,
    const float* __restrict__ Wk, const float* __restrict__ Wv,
    unsigned short* __restrict__ xb, unsigned short* __restrict__ Wb) {
  const long X4 = (long)8192 * 1024 / 4;  // x in float4 units
  const long W4 = (long)1024 * 1024 / 4;
  long i = (long)blockIdx.x * 256 + threadIdx.x;
  const float* src; unsigned short* dst; long off;
  if (i < X4)             { src = x;  dst = xb;                    off = i; }
  else if (i < X4 + W4)   { src = Wq; dst = Wb;                    off = i - X4; }
  else if (i < X4 + 2*W4) { src = Wk; dst = Wb + (long)1024*1024;  off = i - X4 - W4; }
  else                    { src = Wv; dst = Wb + (long)2048*1024;  off = i - X4 - 2*W4; }
  const float4 v = ((const float4*)src)[off];
  ushort4 o;
  o.x = f2bf(v.x); o.y = f2bf(v.y); o.z = f2bf(v.z); o.w = f2bf(v.w);
  ((ushort4*)dst)[off] = o;
}

// ---------------------------------------------------------------------------
// C[M,N] = scale * (A[M,K] x B[N,K]^T) (+ bias[col]); bf16 A/B, fp32 acc.
// 256 threads = 4 waves; wave w owns a 64x64 quadrant (4x4 16x16x32 frags).
// LDS tile [128 rows][4 granules of 16B], granule slot swizzled:
//   slot(row,kc) = ((kc + (row>>1)) & 3)   -> conflict-free b128 frag reads.
// ---------------------------------------------------------------------------
template <bool HAS_BIAS, bool OUT_BF16>
__global__ __launch_bounds__(256) void gemm_bt(
    const unsigned short* __restrict__ Ab, const unsigned short* __restrict__ Bb,
    unsigned short* __restrict__ Cb, float* __restrict__ Cf,
    const float* __restrict__ bias0, const float* __restrict__ bias1,
    const float* __restrict__ bias2,
    int K, int N, float scale, long sA, long sB, long sC) {
  __shared__ unsigned short As[128 * 32];
  __shared__ unsigned short Bs[128 * 32];

  const int z = blockIdx.z;
  const unsigned short* A  = Ab + (long)z * sA;
  const unsigned short* Bm = Bb + (long)z * sB;

  const int tid  = threadIdx.x;
  const int lane = tid & 63;
  const int wave = tid >> 6;
  const int l15  = lane & 15;
  const int quad = lane >> 4;
  const int wm = (wave >> 1) * 64;
  const int wn = (wave & 1) * 64;

  const int tile_m = blockIdx.x * 128;
  const int tile_n = blockIdx.y * 128;

  // --- staging map (swizzled) ---
  // lane L -> LDS granule (wave*16 + (L>>2) row, slot L&3); its content must
  // be global k-chunk kc = (slot - (row>>1)) & 3 of that row.
  const int Lrow = lane >> 2;                       // 0..15 row within strip
  const int slot = lane & 3;
  const int kc   = (slot - (wave * 8 + (Lrow >> 1))) & 3;  // same for both p-halves

  const long lK = (long)K;
  const unsigned short* gA0 = A  + (long)(tile_m + wave * 16 + Lrow) * lK + kc * 8;
  const unsigned short* gB0 = Bm + (long)(tile_n + wave * 16 + Lrow) * lK + kc * 8;
  unsigned short* lA = &As[(wave * 16) * 32];
  unsigned short* lB = &Bs[(wave * 16) * 32];

  // --- fragment read addresses (loop-invariant, swizzle folded) ---
  const int fa = (quad + ((wm + l15) >> 1)) & 3;
  const int fb = (quad + ((wn + l15) >> 1)) & 3;

  f32x4 acc[4][4] = {};

  for (int k0 = 0; k0 < K; k0 += 32) {
    __syncthreads();  // previous-iter LDS readers done
    async_copy16(gA0 + k0, lA);
    async_copy16(gA0 + 64 * lK + k0, lA + 64 * 32);
    async_copy16(gB0 + k0, lB);
    async_copy16(gB0 + 64 * lK + k0, lB + 64 * 32);
    __syncthreads();  // vmcnt(0) drain: LDS tile ready

    bf16x8 af[4], bfr[4];
#pragma unroll
    for (int i = 0; i < 4; ++i)
      af[i] = *(const bf16x8*)&As[(wm + i * 16 + l15) * 32 + fa * 8];
#pragma unroll
    for (int j = 0; j < 4; ++j)
      bfr[j] = *(const bf16x8*)&Bs[(wn + j * 16 + l15) * 32 + fb * 8];
#pragma unroll
    for (int i = 0; i < 4; ++i)
#pragma unroll
      for (int j = 0; j < 4; ++j)
        acc[i][j] = __builtin_amdgcn_mfma_f32_16x16x32_bf16(af[i], bfr[j], acc[i][j], 0, 0, 0);
  }

  // epilogue: C/D layout col=lane&15, row=quad*4+reg (m89-verified)
  const float* bias = bias0;
  if (HAS_BIAS) { if (z == 1) bias = bias1; else if (z == 2) bias = bias2; }

  unsigned short* Cbz = Cb ? Cb + (long)z * sC : nullptr;
  float* Cfz = Cf ? Cf + (long)z * sC : nullptr;

#pragma unroll
  for (int j = 0; j < 4; ++j) {
    const int col = tile_n + wn + j * 16 + l15;
    const float bv = HAS_BIAS ? bias[col] : 0.0f;
#pragma unroll
    for (int i = 0; i < 4; ++i) {
      const int row0 = tile_m + wm + i * 16 + quad * 4;
#pragma unroll
      for (int r = 0; r < 4; ++r) {
        const float v = acc[i][j][r] * scale + bv;
        if (OUT_BF16) Cbz[(long)(row0 + r) * N + col] = f2bf(v);
        else          Cfz[(long)(row0 + r) * N + col] = v;
      }
    }
  }
}

// ---------------------------------------------------------------------------
// V [b][s][f] -> VT [b][f][s]   (bf16, 32x32 LDS tiles, padded)
// ---------------------------------------------------------------------------
__global__ void transpose_v(const unsigned short* __restrict__ V,
                            unsigned short* __restrict__ VT) {
  __shared__ unsigned short t[32][33];
  const int b  = blockIdx.z;
  const int s0 = blockIdx.x * 32;
  const int f0 = blockIdx.y * 32;
  const int tx = threadIdx.x;  // 0..31
  const int ty = threadIdx.y;  // 0..7
  const unsigned short* Vb = V + (long)b * 2048 * 1024;
  unsigned short* VTb = VT + (long)b * 1024 * 2048;
#pragma unroll
  for (int j = 0; j < 4; ++j)
    t[ty + j * 8][tx] = Vb[(long)(s0 + ty + j * 8) * 1024 + f0 + tx];
  __syncthreads();
#pragma unroll
  for (int j = 0; j < 4; ++j)
    VTb[(long)(f0 + ty + j * 8) * 2048 + s0 + tx] = t[tx][ty + j * 8];
}

// ---------------------------------------------------------------------------
// In-place row softmax over bf16 scores: 8192 rows x 2048.
// ---------------------------------------------------------------------------
__global__ __launch_bounds__(256) void softmax_rows(unsigned short* __restrict__ S) {
  __shared__ float red[4];
  unsigned short* p = S + (long)blockIdx.x * 2048;
  const int tid = threadIdx.x;

  uint4 raw = ((const uint4*)p)[tid];  // 8 bf16
  const uint32_t* rw = (const uint32_t*)&raw;
  float v[8];
#pragma unroll
  for (int i = 0; i < 4; ++i) {
    v[2 * i]     = bf2f((unsigned short)(rw[i] & 0xffffu));
    v[2 * i + 1] = bf2f((unsigned short)(rw[i] >> 16));
  }
  float m = v[0];
#pragma unroll
  for (int i = 1; i < 8; ++i) m = fmaxf(m, v[i]);
#pragma unroll
  for (int o = 32; o > 0; o >>= 1) m = fmaxf(m, __shfl_xor(m, o));
  const int wv = tid >> 6;
  if ((tid & 63) == 0) red[wv] = m;
  __syncthreads();
  m = fmaxf(fmaxf(red[0], red[1]), fmaxf(red[2], red[3]));

  float s = 0.0f;
#pragma unroll
  for (int i = 0; i < 8; ++i) { v[i] = __expf(v[i] - m); s += v[i]; }
#pragma unroll
  for (int o = 32; o > 0; o >>= 1) s += __shfl_xor(s, o);
  __syncthreads();  // protect red before reuse
  if ((tid & 63) == 0) red[wv] = s;
  __syncthreads();
  s = red[0] + red[1] + red[2] + red[3];
  const float inv = 1.0f / s;

  uint32_t outw[4];
#pragma unroll
  for (int i = 0; i < 4; ++i) {
    const unsigned short lo = f2bf(v[2 * i] * inv);
    const unsigned short hi = f2bf(v[2 * i + 1] * inv);
    outw[i] = (uint32_t)lo | ((uint32_t)hi << 16);
  }
  ((uint4*)p)[tid] = *(uint4*)outw;
}

// ---------------------------------------------------------------------------
extern "C" void kernel_launch(void* const* d_in, const int* in_sizes, int n_in,
                              void* d_out, int out_size, void* d_ws, size_t ws_size,
                              hipStream_t stream) {
  const float* x  = (const float*)d_in[0];
  const float* Wq = (const float*)d_in[1];
  const float* bq = (const float*)d_in[2];
  const float* Wk = (const float*)d_in[3];
  const float* bk = (const float*)d_in[4];
  const float* Wv = (const float*)d_in[5];
  const float* bv = (const float*)d_in[6];
  float* out = (float*)d_out;

  constexpr int Bt = 4, S = 2048, E = 1024;
  constexpr int M = Bt * S;  // 8192 tokens

  // ws layout (bf16): x_bf | W_bf(3) | Q | K | V | VT | P(scores)
  unsigned short* xb  = (unsigned short*)d_ws;
  unsigned short* Wb  = xb + (size_t)M * E;
  unsigned short* QKV = Wb + (size_t)3 * E * E;
  unsigned short* Q   = QKV;
  unsigned short* Kb  = QKV + (size_t)M * E;
  unsigned short* V   = QKV + (size_t)2 * M * E;
  unsigned short* VT  = QKV + (size_t)3 * M * E;
  unsigned short* P   = VT + (size_t)M * E;
  // total = (M*E*5 + 3*E*E + Bt*S*S) * 2 B ~= 124 MB

  // 1) converts (one launch)
  const int conv_blocks = (M * E / 4 + 3 * (E * E / 4)) / 256;  // 11264
  convert_all<<<dim3(conv_blocks), dim3(256), 0, stream>>>(x, Wq, Wk, Wv, xb, Wb);

  // 2) projections: z in {Q,K,V}; y = x * W^T + b
  gemm_bt<true, true><<<dim3(M / 128, E / 128, 3), dim3(256), 0, stream>>>(
      xb, Wb, QKV, nullptr, bq, bk, bv, E, E, 1.0f,
      0L, (long)E * E, (long)M * E);

  // 3) V -> VT
  transpose_v<<<dim3(S / 32, E / 32, Bt), dim3(32, 8), 0, stream>>>(V, VT);

  // 4) scores = Q K^T / 32
  gemm_bt<false, true><<<dim3(S / 128, S / 128, Bt), dim3(256), 0, stream>>>(
      Q, Kb, P, nullptr, nullptr, nullptr, nullptr, E, S, 1.0f / 32.0f,
      (long)S * E, (long)S * E, (long)S * S);

  // 5) softmax rows (in place)
  softmax_rows<<<dim3(M), dim3(256), 0, stream>>>(P);

  // 6) out = P V = P * (VT)^T   (fp32 out)
  gemm_bt<false, false><<<dim3(S / 128, E / 128, Bt), dim3(256), 0, stream>>>(
      P, VT, nullptr, out, nullptr, nullptr, nullptr, S, E, 1.0f,
      (long)S * S, (long)E * S, (long)S * E);
}

// Round 3
// 266.568 us; speedup vs baseline: 1.1682x; 1.1071x over previous
//
#include <hip/hip_runtime.h>
#include <hip/hip_bf16.h>
#include <cstdint>

// ---------------------------------------------------------------------------
// AttentionModel: out = softmax((xWq^T+bq)(xWk^T+bk)^T / 32) (xWv^T+bv)
// B=4, S=2048, E=1024, fp32 in/out.  bf16 MFMA pipeline.
// R3 changes:
//  - BK=64 K-loop (half the barrier/vmcnt drains; LDS 32KB keeps occupancy)
//  - scores epilogue stores exp(s/32) (unnormalized) + atomic row-sums;
//    PV epilogue multiplies by 1/rowsum  -> softmax kernel deleted
//  - proj epilogue writes V transposed directly -> transpose kernel deleted
// LDS swizzle (BK=64): row=8 granules of 16B, physical slot = kc ^ (row&7);
// conflict-free b128 frag reads; staging lane L stages chunk (L&7)^(L>>3).
// ---------------------------------------------------------------------------

typedef __attribute__((ext_vector_type(8))) short bf16x8;
typedef __attribute__((ext_vector_type(4))) float f32x4;

__device__ __forceinline__ unsigned short f2bf(float f) {
  union { float f; uint32_t u; } x; x.f = f;
  uint32_t u = x.u;
  return (unsigned short)((u + 0x7fffu + ((u >> 16) & 1u)) >> 16);  // RNE
}

__device__ __forceinline__ void async_copy16(const void* g, void* l) {
  __builtin_amdgcn_global_load_lds(
      (const __attribute__((address_space(1))) void*)g,
      (__attribute__((address_space(3))) void*)l, 16, 0, 0);
}

// ---------------------------------------------------------------------------
// One merged fp32->bf16 convert for x, Wq, Wk, Wv
// ---------------------------------------------------------------------------
__global__ __launch_bounds__(256) void convert_all(
    const float* __restrict__ x, const float* __restrict__ Wq,
    const float* __restrict__ Wk, const float* __restrict__ Wv,
    unsigned short* __restrict__ xb, unsigned short* __restrict__ Wb) {
  const long X4 = (long)8192 * 1024 / 4;
  const long W4 = (long)1024 * 1024 / 4;
  long i = (long)blockIdx.x * 256 + threadIdx.x;
  const float* src; unsigned short* dst; long off;
  if (i < X4)             { src = x;  dst = xb;                    off = i; }
  else if (i < X4 + W4)   { src = Wq; dst = Wb;                    off = i - X4; }
  else if (i < X4 + 2*W4) { src = Wk; dst = Wb + (long)1024*1024;  off = i - X4 - W4; }
  else                    { src = Wv; dst = Wb + (long)2048*1024;  off = i - X4 - 2*W4; }
  const float4 v = ((const float4*)src)[off];
  ushort4 o;
  o.x = f2bf(v.x); o.y = f2bf(v.y); o.z = f2bf(v.z); o.w = f2bf(v.w);
  ((ushort4*)dst)[off] = o;
}

// ---------------------------------------------------------------------------
// C[M,N] = op( scale * (A[M,K] x B[N,K]^T) + bias )
// MODE 0 (PROJ):   bf16 out; z<2 -> normal rows; z==2 -> write V transposed
// MODE 1 (SCORES): bf16 out = exp(scale*acc); atomicAdd per-row sums
// MODE 2 (PV):     fp32 out = acc * (1/rowsum[row])
// 256 threads = 4 waves, 128x128 tile, BK=64, 16x16x32 bf16 MFMA.
// ---------------------------------------------------------------------------
template <int MODE>
__global__ __launch_bounds__(256) void gemm_bt(
    const unsigned short* __restrict__ Ab, const unsigned short* __restrict__ Bb,
    unsigned short* __restrict__ Cb, float* __restrict__ Cf,
    unsigned short* __restrict__ VT,
    const float* __restrict__ bias0, const float* __restrict__ bias1,
    const float* __restrict__ bias2, float* __restrict__ rowsum,
    int K, int N, float scale, long sA, long sB, long sC) {
  __shared__ unsigned short As[128 * 64];
  __shared__ unsigned short Bs[128 * 64];

  const int z = blockIdx.z;
  const unsigned short* A  = Ab + (long)z * sA;
  const unsigned short* Bm = Bb + (long)z * sB;

  const int tid  = threadIdx.x;
  const int lane = tid & 63;
  const int wave = tid >> 6;
  const int l15  = lane & 15;
  const int quad = lane >> 4;
  const int wm = (wave >> 1) * 64;
  const int wn = (wave & 1) * 64;

  const int tile_m = blockIdx.x * 128;
  const int tile_n = blockIdx.y * 128;

  // --- staging map: wave w covers rows [w*32, w*32+32) of both tiles,
  // 4 instructions each (8 rows per instruction). Lane L -> LDS slot L&7 of
  // row strip_base + (L>>3); content = logical k-chunk (L&7)^(L>>3).
  const int rs8 = lane >> 3;
  const int kc  = (lane & 7) ^ rs8;
  const long lK = (long)K;
  const unsigned short* gA0 = A  + (long)(tile_m + wave * 32 + rs8) * lK + kc * 8;
  const unsigned short* gB0 = Bm + (long)(tile_n + wave * 32 + rs8) * lK + kc * 8;
  unsigned short* lA = &As[(wave * 32) * 64];
  unsigned short* lB = &Bs[(wave * 32) * 64];

  // --- fragment granule select: physical = (s*4+quad) ^ (row&7), row&7 = l15&7
  const int g0 = (0 * 4 + quad) ^ (l15 & 7);
  const int g1 = (1 * 4 + quad) ^ (l15 & 7);

  f32x4 acc[4][4] = {};

  for (int k0 = 0; k0 < K; k0 += 64) {
    __syncthreads();  // previous-iter LDS readers done
#pragma unroll
    for (int t = 0; t < 4; ++t) {
      async_copy16(gA0 + (long)t * 8 * lK + k0, lA + t * 8 * 64);
      async_copy16(gB0 + (long)t * 8 * lK + k0, lB + t * 8 * 64);
    }
    __syncthreads();  // drain: LDS tile ready

#pragma unroll
    for (int s = 0; s < 2; ++s) {
      const int gs = s ? g1 : g0;
      bf16x8 af[4], bfr[4];
#pragma unroll
      for (int i = 0; i < 4; ++i)
        af[i] = *(const bf16x8*)&As[(wm + i * 16 + l15) * 64 + gs * 8];
#pragma unroll
      for (int j = 0; j < 4; ++j)
        bfr[j] = *(const bf16x8*)&Bs[(wn + j * 16 + l15) * 64 + gs * 8];
#pragma unroll
      for (int i = 0; i < 4; ++i)
#pragma unroll
        for (int j = 0; j < 4; ++j)
          acc[i][j] = __builtin_amdgcn_mfma_f32_16x16x32_bf16(af[i], bfr[j], acc[i][j], 0, 0, 0);
    }
  }

  // ------------------------- epilogue -------------------------
  // C/D layout: col = lane&15, row = quad*4 + reg (m89-verified)
  if (MODE == 0) {
    const float* bias = (z == 0) ? bias0 : (z == 1) ? bias1 : bias2;
    if (z == 2) {
      // write V transposed: VT[b][f][s], b = row>>11, s = row&2047
#pragma unroll
      for (int j = 0; j < 4; ++j) {
        const int col = tile_n + wn + j * 16 + l15;  // feature f
        const float bv = bias[col];
#pragma unroll
        for (int i = 0; i < 4; ++i) {
          const int row0 = tile_m + wm + i * 16 + quad * 4;  // token
          const int b = row0 >> 11;
          const int s = row0 & 2047;
          ushort4 o;
          o.x = f2bf(acc[i][j][0] + bv);
          o.y = f2bf(acc[i][j][1] + bv);
          o.z = f2bf(acc[i][j][2] + bv);
          o.w = f2bf(acc[i][j][3] + bv);
          *(ushort4*)&VT[(long)b * 1024 * 2048 + (long)col * 2048 + s] = o;
        }
      }
    } else {
      unsigned short* Cbz = Cb + (long)z * sC;
#pragma unroll
      for (int j = 0; j < 4; ++j) {
        const int col = tile_n + wn + j * 16 + l15;
        const float bv = bias[col];
#pragma unroll
        for (int i = 0; i < 4; ++i) {
          const int row0 = tile_m + wm + i * 16 + quad * 4;
#pragma unroll
          for (int r = 0; r < 4; ++r)
            Cbz[(long)(row0 + r) * N + col] = f2bf(acc[i][j][r] + bv);
        }
      }
    }
  } else if (MODE == 1) {
    // exp epilogue + row-sum atomics
    unsigned short* Cbz = Cb + (long)z * sC;
    float part[16];
#pragma unroll
    for (int t = 0; t < 16; ++t) part[t] = 0.0f;
#pragma unroll
    for (int j = 0; j < 4; ++j) {
      const int col = tile_n + wn + j * 16 + l15;
#pragma unroll
      for (int i = 0; i < 4; ++i) {
        const int row0 = tile_m + wm + i * 16 + quad * 4;
#pragma unroll
        for (int r = 0; r < 4; ++r) {
          const float e = __expf(acc[i][j][r] * scale);
          part[i * 4 + r] += e;
          Cbz[(long)(row0 + r) * N + col] = f2bf(e);
        }
      }
    }
    // reduce across the 16 lanes (l15) sharing each row
#pragma unroll
    for (int t = 0; t < 16; ++t)
#pragma unroll
      for (int o = 1; o < 16; o <<= 1)
        part[t] += __shfl_xor(part[t], o);
    if (l15 == 0) {
#pragma unroll
      for (int i = 0; i < 4; ++i) {
        const int row0 = tile_m + wm + i * 16 + quad * 4;
#pragma unroll
        for (int r = 0; r < 4; ++r)
          atomicAdd(&rowsum[z * 2048 + row0 + r], part[i * 4 + r]);
      }
    }
  } else {
    // PV: normalize by rowsum
    float* Cfz = Cf + (long)z * sC;
    float inv[16];
#pragma unroll
    for (int i = 0; i < 4; ++i) {
      const int row0 = tile_m + wm + i * 16 + quad * 4;
#pragma unroll
      for (int r = 0; r < 4; ++r)
        inv[i * 4 + r] = 1.0f / rowsum[z * 2048 + row0 + r];
    }
#pragma unroll
    for (int j = 0; j < 4; ++j) {
      const int col = tile_n + wn + j * 16 + l15;
#pragma unroll
      for (int i = 0; i < 4; ++i) {
        const int row0 = tile_m + wm + i * 16 + quad * 4;
#pragma unroll
        for (int r = 0; r < 4; ++r)
          Cfz[(long)(row0 + r) * N + col] = acc[i][j][r] * inv[i * 4 + r];
      }
    }
  }
}

// ---------------------------------------------------------------------------
extern "C" void kernel_launch(void* const* d_in, const int* in_sizes, int n_in,
                              void* d_out, int out_size, void* d_ws, size_t ws_size,
                              hipStream_t stream) {
  const float* x  = (const float*)d_in[0];
  const float* Wq = (const float*)d_in[1];
  const float* bq = (const float*)d_in[2];
  const float* Wk = (const float*)d_in[3];
  const float* bk = (const float*)d_in[4];
  const float* Wv = (const float*)d_in[5];
  const float* bv = (const float*)d_in[6];
  float* out = (float*)d_out;

  constexpr int Bt = 4, S = 2048, E = 1024;
  constexpr int M = Bt * S;  // 8192

  // ws layout (bf16): x_bf | W_bf(3) | Q | K | VT | P(exp scores) | rowsum(f32)
  unsigned short* xb = (unsigned short*)d_ws;
  unsigned short* Wb = xb + (size_t)M * E;
  unsigned short* Q  = Wb + (size_t)3 * E * E;
  unsigned short* Kb = Q + (size_t)M * E;
  unsigned short* VT = Kb + (size_t)M * E;
  unsigned short* P  = VT + (size_t)M * E;
  float* rowsum = (float*)(P + (size_t)Bt * S * S);
  // total ~= 107 MB + 32 KB

  // 0) zero the row-sum accumulators (ws is poisoned 0xAA each launch)
  hipMemsetAsync(rowsum, 0, (size_t)M * sizeof(float), stream);

  // 1) converts
  const int conv_blocks = (M * E / 4 + 3 * (E * E / 4)) / 256;
  convert_all<<<dim3(conv_blocks), dim3(256), 0, stream>>>(x, Wq, Wk, Wv, xb, Wb);

  // 2) projections: z in {Q,K,V}; y = x W^T + b; V written transposed
  gemm_bt<0><<<dim3(M / 128, E / 128, 3), dim3(256), 0, stream>>>(
      xb, Wb, Q, nullptr, VT, bq, bk, bv, nullptr, E, E, 1.0f,
      0L, (long)E * E, (long)M * E);

  // 3) P = exp(Q K^T / 32) (unnormalized) + row sums
  gemm_bt<1><<<dim3(S / 128, S / 128, Bt), dim3(256), 0, stream>>>(
      Q, Kb, P, nullptr, nullptr, nullptr, nullptr, nullptr, rowsum,
      E, S, 1.0f / 32.0f, (long)S * E, (long)S * E, (long)S * S);

  // 4) out = (P V) / rowsum   (fp32 out)
  gemm_bt<2><<<dim3(S / 128, E / 128, Bt), dim3(256), 0, stream>>>(
      P, VT, nullptr, out, nullptr, nullptr, nullptr, nullptr, rowsum,
      S, E, 1.0f, (long)S * S, (long)E * S, (long)S * E);
}